// Round 1
// baseline (747.429 us; speedup 1.0000x reference)
//
#include <hip/hip_runtime.h>

// Problem constants (B,C,T,V)=(32,128,64,25), N_STEP=8, DILATION=1
#define CC     128
#define TT     64
#define VV     25
#define BB     32
#define PP     (TT * VV)          // 1600 positions per (b, c)
#define CHUNK  (BB * CC * PP)     // 6,553,600 elems per output chunk
#define NSTEP  8
#define PTILE  64                 // positions per block tile
#define NPT    (PP / PTILE)       // 25 tiles per batch

// ---- tiny one-time kernel: Wt[c][d] = W[d][c] into workspace -------------
__global__ void transpose_w(const float* __restrict__ W, float* __restrict__ Wt) {
    int idx = blockIdx.x * 256 + threadIdx.x;       // 16384 total
    if (idx < CC * CC) {
        int d = idx >> 7;
        int c = idx & (CC - 1);
        Wt[c * CC + d] = W[d * CC + c];
    }
}

__device__ __forceinline__ float fast_tanh(float x) {
    // tanh(x) = 1 - 2/(exp(2x)+1); exp=v_exp_f32, rcp=v_rcp_f32.
    // x->+inf: e=inf -> 1; x->-inf: e=0 -> -1.  ~1e-7 abs err, threshold is 0.2.
    float e = __expf(2.0f * x);
    return 1.0f - 2.0f * __builtin_amdgcn_rcpf(e + 1.0f);
}

// ---- fused 8-step Euler kernel -------------------------------------------
// Block owns (b, 64-position tile) x all 128 channels. State lives in LDS
// across all 8 steps (per-position channel mix => no cross-block deps).
// Thread tile: 8 channels (d) x 4 positions (p) => 32 fp32 accumulators.
__global__ __launch_bounds__(256) void euler_fused(
    const float* __restrict__ z, const float* __restrict__ Wt,
    const float* __restrict__ bias, float* __restrict__ out)
{
    __shared__ float Xs[CC][PTILE];                 // 32 KB state tile

    const int b   = blockIdx.y;
    const int p0  = blockIdx.x * PTILE;
    const int tid = threadIdx.x;
    const int tx  = tid & 15;                       // 16 position groups
    const int ty  = tid >> 4;                       // 16 channel groups
    const int d0  = ty * 8;
    const int px  = tx * 4;

    // ---- load z tile (coalesced float4) + write both chunk-0 outputs ----
    const float* zb = z + (size_t)b * CC * PP + p0;
    #pragma unroll
    for (int it = 0; it < 8; ++it) {
        int f4 = it * 256 + tid;                    // 0..2047 float4 slots
        int c  = f4 >> 4;
        int po = (f4 & 15) * 4;
        float4 v = *(const float4*)(zb + (size_t)c * PP + po);
        *(float4*)&Xs[c][po] = v;
        size_t o = (size_t)(b * CC + c) * PP + p0 + po;
        *(float4*)(out + o)                      = v;  // z_shift chunk 0 (= z)
        *(float4*)(out + (size_t)9 * CHUNK + o)  = v;  // z_cls   chunk 0 (= z)
    }

    float bv[8];
    #pragma unroll
    for (int j = 0; j < 8; ++j) bv[j] = bias[d0 + j];

    __syncthreads();

    for (int i = 1; i <= NSTEP; ++i) {
        float acc[8][4];
        #pragma unroll
        for (int j = 0; j < 8; ++j)
            #pragma unroll
            for (int k = 0; k < 4; ++k) acc[j][k] = 0.0f;

        // ---- channel matmul: acc[d][p] = sum_c W[d][c] * X[c][p] ----
        // Wt rows streamed from L2 (64 KB, cache-resident); X from LDS.
        #pragma unroll 4
        for (int c = 0; c < CC; ++c) {
            const float* wr = Wt + c * CC + d0;
            float4 w0 = *(const float4*)(wr);
            float4 w1 = *(const float4*)(wr + 4);
            float4 x  = *(const float4*)&Xs[c][px];
            float wv[8] = {w0.x, w0.y, w0.z, w0.w, w1.x, w1.y, w1.z, w1.w};
            float xv[4] = {x.x, x.y, x.z, x.w};
            #pragma unroll
            for (int j = 0; j < 8; ++j)
                #pragma unroll
                for (int k = 0; k < 4; ++k)
                    acc[j][k] += wv[j] * xv[k];
        }

        // ---- y = x_old + tanh(acc + bias)  (reads Xs pre-barrier) ----
        #pragma unroll
        for (int j = 0; j < 8; ++j) {
            float4 xo = *(const float4*)&Xs[d0 + j][px];
            acc[j][0] = xo.x + fast_tanh(acc[j][0] + bv[j]);
            acc[j][1] = xo.y + fast_tanh(acc[j][1] + bv[j]);
            acc[j][2] = xo.z + fast_tanh(acc[j][2] + bv[j]);
            acc[j][3] = xo.w + fast_tanh(acc[j][3] + bv[j]);
        }

        __syncthreads();   // all reads of old state done

        // ---- update LDS state + write z_cls / z_shift chunks ----
        const size_t shiftBase = (size_t)i * CHUNK;
        const size_t clsBase   = (size_t)(9 + i) * CHUNK;
        const int s = VV * i;   // flat-position shift (t -> t+i)
        #pragma unroll
        for (int j = 0; j < 8; ++j) {
            float4 y4 = make_float4(acc[j][0], acc[j][1], acc[j][2], acc[j][3]);
            *(float4*)&Xs[d0 + j][px] = y4;

            size_t row = (size_t)(b * CC + d0 + j) * PP;
            *(float4*)(out + clsBase + row + p0 + px) = y4;   // z_cls chunk i

            // z_shift chunk i: out[t+i] = cur[t] (drop t+i>=T); zero t<i.
            #pragma unroll
            for (int e = 0; e < 4; ++e) {
                int p = p0 + px + e;
                int q = p + s;
                if (q < PP) out[shiftBase + row + q] = acc[j][e];
                if (p < s)  out[shiftBase + row + p] = 0.0f;
            }
        }

        __syncthreads();   // state update visible before next step
    }
}

extern "C" void kernel_launch(void* const* d_in, const int* in_sizes, int n_in,
                              void* d_out, int out_size, void* d_ws, size_t ws_size,
                              hipStream_t stream) {
    const float* z    = (const float*)d_in[0];   // (32,128,64,25) fp32
    const float* W    = (const float*)d_in[1];   // (128,128) fp32
    const float* bias = (const float*)d_in[2];   // (128,) fp32
    float* out = (float*)d_out;                  // 18 * CHUNK fp32
    float* Wt  = (float*)d_ws;                   // 64 KB scratch for W^T

    hipLaunchKernelGGL(transpose_w, dim3((CC * CC + 255) / 256), dim3(256), 0, stream, W, Wt);
    hipLaunchKernelGGL(euler_fused, dim3(NPT, BB), dim3(256), 0, stream, z, Wt, bias, out);
}